// Round 6
// baseline (118.924 us; speedup 1.0000x reference)
//
#include <hip/hip_runtime.h>
#include <hip/hip_bf16.h>
#include <math.h>
#include <stdint.h>

typedef unsigned short u16;
typedef __attribute__((ext_vector_type(8))) short bf16x8;
typedef __attribute__((ext_vector_type(4))) float f32x4;

#define MFMA16(A,B,C) __builtin_amdgcn_mfma_f32_16x16x32_bf16(A,B,C,0,0,0)

#define BB 2
#define SS 2048
#define NT (BB*SS)

__device__ __forceinline__ u16 f2bf(float f) {
    union { float f; unsigned u; } c; c.f = f;
    unsigned r = c.u + 0x7FFF + ((c.u >> 16) & 1);
    return (u16)(r >> 16);
}
__device__ __forceinline__ float bf2f(u16 v) {
    union { unsigned u; float f; } c; c.u = ((unsigned)v) << 16;
    return c.f;
}

// async global->LDS, 16B per lane. LDS dest = wave-uniform base + lane*16B.
__device__ __forceinline__ void gl_lds16(const u16* g, u16* l) {
    __builtin_amdgcn_global_load_lds(
        (const __attribute__((address_space(1))) void*)(uintptr_t)g,
        (__attribute__((address_space(3))) void*)(uintptr_t)l, 16, 0, 0);
}

// ---------------- fp32 -> bf16 elementwise cast
__global__ __launch_bounds__(256) void cast_bf16(const float* __restrict__ in,
                                                 u16* __restrict__ out, int n) {
    int i = (blockIdx.x * 256 + threadIdx.x) * 4;
    if (i < n) {
        float4 v = *(const float4*)&in[i];
        ushort4 o;
        o.x = f2bf(v.x); o.y = f2bf(v.y); o.z = f2bf(v.z); o.w = f2bf(v.w);
        *(ushort4*)&out[i] = o;
    }
}

// ---------------- fp32 [1024][M] -> bf16 transposed [M][1024]
__global__ __launch_bounds__(256) void transpose_cast(const float* __restrict__ in,
                                                      u16* __restrict__ out, int M) {
    __shared__ float tile[64][65];
    const int k0 = blockIdx.x * 64, m0 = blockIdx.y * 64;
    const int t = threadIdx.x;
    #pragma unroll
    for (int rep = 0; rep < 16; ++rep) {
        int idx = rep * 256 + t;
        int kk = idx >> 6, mm = idx & 63;
        tile[kk][mm] = in[(size_t)(k0 + kk) * M + m0 + mm];
    }
    __syncthreads();
    #pragma unroll
    for (int rep = 0; rep < 16; ++rep) {
        int idx = rep * 256 + t;
        int mm = idx >> 6, kk = idx & 63;
        out[(size_t)(m0 + mm) * 1024 + k0 + kk] = f2bf(tile[kk][mm]);
    }
}

// ---------------- V pre-transpose: qkvb V-part [token][h*64+d] -> vtg[bh*64+d][token]
// grid (32 bh, 32 token-tiles); plain (unswizzled) output layout.
__global__ __launch_bounds__(256) void transpose_v(const u16* __restrict__ qkvb,
                                                   u16* __restrict__ vtg) {
    __shared__ u16 tile[64][72];   // [token][d], 16B-aligned rows
    const int bh = blockIdx.x, kt = blockIdx.y;
    const int b = bh >> 4, h = bh & 15;
    const int t = threadIdx.x;
    const int tt = t >> 2;
    #pragma unroll
    for (int r = 0; r < 2; ++r) {
        int c = (t & 3) + r * 4;   // 16B chunk of the 64-d row
        *(bf16x8*)&tile[tt][c * 8] =
            *(const bf16x8*)&qkvb[(size_t)(b * SS + kt * 64 + tt) * 3072 + 2048 + h * 64 + c * 8];
    }
    __syncthreads();
    const int d = t >> 2;
    #pragma unroll
    for (int r = 0; r < 2; ++r) {
        int c16 = (t & 3) + r * 4;  // out 16B chunk = tokens c16*8..+7
        ushort4 o0, o1;
        o0.x = tile[c16 * 8 + 0][d]; o0.y = tile[c16 * 8 + 1][d];
        o0.z = tile[c16 * 8 + 2][d]; o0.w = tile[c16 * 8 + 3][d];
        o1.x = tile[c16 * 8 + 4][d]; o1.y = tile[c16 * 8 + 5][d];
        o1.z = tile[c16 * 8 + 6][d]; o1.w = tile[c16 * 8 + 7][d];
        u16* dst = &vtg[(size_t)(bh * 64 + d) * SS + kt * 64 + c16 * 8];
        *(ushort4*)dst = o0;
        *(ushort4*)(dst + 4) = o1;
    }
}

// ---------------- bf16 MFMA GEMM with global_load_lds staging (m97 pattern)
template<int MD, typename OutT>
__global__ __launch_bounds__(256) void gemm_bt(const u16* __restrict__ A,
                                               const u16* __restrict__ BT,
                                               const float* __restrict__ bias,
                                               OutT* __restrict__ C) {
    __shared__ u16 As[128 * 32];
    __shared__ u16 Bs[128 * 32];
    const int t = threadIdx.x;
    const int lane = t & 63;
    const int w = t >> 6;
    const int wr = (w >> 1) * 64, wc = (w & 1) * 64;
    const int ln = lane & 15, hi = lane >> 4;
    const int n0 = blockIdx.x * 128;
    const int m0 = blockIdx.y * 128;

    f32x4 acc[4][4];
    const f32x4 fz = {0.f, 0.f, 0.f, 0.f};
    #pragma unroll
    for (int i = 0; i < 4; ++i)
        #pragma unroll
        for (int j = 0; j < 4; ++j) acc[i][j] = fz;

    const int srow_in = lane >> 2;
    const int schunk  = lane & 3;

    for (int k0 = 0; k0 < 1024; k0 += 32) {
        __syncthreads();
        #pragma unroll
        for (int p = 0; p < 2; ++p) {
            int q   = w * 2 + p;
            int row = q * 16 + srow_in;
            int cg  = schunk ^ (row & 3);
            gl_lds16(&A [(size_t)(n0 + row) * 1024 + k0 + cg * 8], &As[q * 512]);
            gl_lds16(&BT[(size_t)(m0 + row) * 1024 + k0 + cg * 8], &Bs[q * 512]);
        }
        __syncthreads();
        bf16x8 af[4], bf[4];
        #pragma unroll
        for (int mi = 0; mi < 4; ++mi) {
            int r = wr + mi * 16 + ln;
            af[mi] = *(const bf16x8*)&As[r * 32 + ((hi ^ (r & 3)) << 3)];
        }
        #pragma unroll
        for (int ni = 0; ni < 4; ++ni) {
            int r = wc + ni * 16 + ln;
            bf[ni] = *(const bf16x8*)&Bs[r * 32 + ((hi ^ (r & 3)) << 3)];
        }
        #pragma unroll
        for (int mi = 0; mi < 4; ++mi)
            #pragma unroll
            for (int ni = 0; ni < 4; ++ni)
                acc[mi][ni] = MFMA16(af[mi], bf[ni], acc[mi][ni]);
    }

    #pragma unroll
    for (int mi = 0; mi < 4; ++mi) {
        #pragma unroll
        for (int ni = 0; ni < 4; ++ni) {
            int col = m0 + wc + ni * 16 + ln;
            float bv = bias[col];
            #pragma unroll
            for (int r = 0; r < 4; ++r) {
                int row = n0 + wr + mi * 16 + hi * 4 + r;
                float v = acc[mi][ni][r] + bv;
                if constexpr (sizeof(OutT) == 4) C[(size_t)row * MD + col] = v;
                else                             C[(size_t)row * MD + col] = (OutT)f2bf(v);
            }
        }
    }
}

// ---------------- MFMA flash attention (bf16), fully DMA-staged K and V^T,
// 2-phase double buffer (issue next-tile DMA before compute; __syncthreads'
// vmcnt(0)+barrier drains it after compute).
__global__ __launch_bounds__(256) void attn_mfma(const u16* __restrict__ qkv,
                                                 const u16* __restrict__ vtg,
                                                 u16* __restrict__ ctx) {
    __shared__ u16 Ks[2][64 * 64];  // [key][8B chunk c], c holds global c^(key&7) (8B units via 16B DMA)
    __shared__ u16 Vs[2][64 * 64];  // [d][8B chunk p], p holds src 8B chunk p^((d&7)<<1)
    const int bh = blockIdx.x;
    const int qt = 31 - blockIdx.y;          // longest-first (LPT)
    const int b = bh >> 4, h = bh & 15;
    const int t = threadIdx.x, w = t >> 6, lane = t & 63;
    const int ln = lane & 15, hi = lane >> 4;
    const int qrow = qt * 64 + w * 16 + ln;
    const size_t tok = (size_t)b * SS;

    // Q fragment (B operand of S^T): k = t2*32 + hi*8 + i, scaled by 1/8
    bf16x8 qb[2];
    #pragma unroll
    for (int t2 = 0; t2 < 2; ++t2) {
        bf16x8 v = *(const bf16x8*)&qkv[(tok + qrow) * 3072 + h * 64 + t2 * 32 + hi * 8];
        #pragma unroll
        for (int i = 0; i < 8; ++i)
            v[i] = (short)f2bf(bf2f((u16)v[i]) * 0.125f);
        qb[t2] = v;
    }

    float m_run = -1e30f, l_run = 0.f;
    f32x4 o[4];
    const f32x4 fz = {0.f, 0.f, 0.f, 0.f};
    #pragma unroll
    for (int i = 0; i < 4; ++i) o[i] = fz;

    // staging lane maps
    const int kkey_l = w * 8 + (lane >> 3);            // K row, + p*32
    const int ksch   = lane & 7;                        // K 16B chunk
    const int vrow_l = lane >> 3;                       // V row within 8-group
    const int vsch   = (lane & 7) ^ (lane >> 3);        // pre-swizzled V src 16B chunk

    const size_t vbase = (size_t)bh * 64 * SS;

    // prologue: stage tile 0 into buffer 0
    {
        const size_t kvb = (tok /*+ 0*/) * 3072 + h * 64;
        #pragma unroll
        for (int p = 0; p < 2; ++p) {
            int kk = p * 32 + kkey_l;
            gl_lds16(&qkv[kvb + (size_t)kk * 3072 + 1024 + ((ksch ^ (kk & 7)) << 3)],
                     &Ks[0][(p * 32 + w * 8) * 64]);
            int d = w * 16 + p * 8 + vrow_l;
            gl_lds16(&vtg[vbase + (size_t)d * SS + (vsch << 3)],
                     &Vs[0][(w * 16 + p * 8) * 64]);
        }
    }

    for (int kt = 0; kt <= qt; ++kt) {
        const int cur = kt & 1;
        __syncthreads();   // drains DMA for buf[cur] (vmcnt0 before barrier) + syncs readers

        if (kt < qt) {     // issue next-tile DMA into the other buffer
            const int nxt = cur ^ 1;
            const size_t kvb = (tok + (kt + 1) * 64) * 3072 + h * 64;
            #pragma unroll
            for (int p = 0; p < 2; ++p) {
                int kk = p * 32 + kkey_l;
                gl_lds16(&qkv[kvb + (size_t)kk * 3072 + 1024 + ((ksch ^ (kk & 7)) << 3)],
                         &Ks[nxt][(p * 32 + w * 8) * 64]);
                int d = w * 16 + p * 8 + vrow_l;
                gl_lds16(&vtg[vbase + (size_t)d * SS + (kt + 1) * 64 + (vsch << 3)],
                         &Vs[nxt][(w * 16 + p * 8) * 64]);
            }
        }

        // S^T = K . Q^T : 4 key sub-tiles of 16
        f32x4 sacc[4];
        #pragma unroll
        for (int s = 0; s < 4; ++s) {
            int key = s * 16 + ln;
            f32x4 a = fz;
            #pragma unroll
            for (int t2 = 0; t2 < 2; ++t2) {
                bf16x8 kf = *(const bf16x8*)&Ks[cur][key * 64 + (((t2 * 4 + hi) ^ (key & 7)) << 3)];
                a = MFMA16(kf, qb[t2], a);
            }
            sacc[s] = a;
        }

        // online softmax (lane owns one q-row; reduce over hi via 2 shfls)
        float p_[16];
        float mloc = -1e30f;
        if (kt == qt) {
            #pragma unroll
            for (int s = 0; s < 4; ++s)
                #pragma unroll
                for (int r = 0; r < 4; ++r) {
                    int keyg = kt * 64 + s * 16 + hi * 4 + r;
                    float v = (keyg <= qrow) ? sacc[s][r] : -1e30f;
                    p_[s * 4 + r] = v;
                    mloc = fmaxf(mloc, v);
                }
        } else {
            #pragma unroll
            for (int s = 0; s < 4; ++s)
                #pragma unroll
                for (int r = 0; r < 4; ++r) {
                    float v = sacc[s][r];
                    p_[s * 4 + r] = v;
                    mloc = fmaxf(mloc, v);
                }
        }
        mloc = fmaxf(mloc, __shfl_xor(mloc, 16));
        mloc = fmaxf(mloc, __shfl_xor(mloc, 32));
        float m_new = fmaxf(m_run, mloc);
        float alpha = __expf(m_run - m_new);
        float lsum = 0.f;
        #pragma unroll
        for (int i = 0; i < 16; ++i) {
            float e = __expf(p_[i] - m_new);
            p_[i] = e;
            lsum += e;
        }
        lsum += __shfl_xor(lsum, 16);
        lsum += __shfl_xor(lsum, 32);
        l_run = l_run * alpha + lsum;
        m_run = m_new;
        #pragma unroll
        for (int dt = 0; dt < 4; ++dt) o[dt] *= alpha;

        // P -> bf16 fragments via packed convert (identity key bijection)
        bf16x8 pa[2];
        #pragma unroll
        for (int k2 = 0; k2 < 2; ++k2) {
            union { unsigned wd[4]; bf16x8 v; } pu;
            #pragma unroll
            for (int qi = 0; qi < 4; ++qi)
                asm("v_cvt_pk_bf16_f32 %0, %1, %2"
                    : "=v"(pu.wd[qi])
                    : "v"(p_[k2 * 8 + 2 * qi]), "v"(p_[k2 * 8 + 2 * qi + 1]));
            pa[k2] = pu.v;
        }

        // O^T += V^T . P^T ; va slot i = V[key k2*32+16*(i>>2)+hi*4+(i&3)][d]
        #pragma unroll
        for (int dt = 0; dt < 4; ++dt) {
            const u16* row = &Vs[cur][(dt * 16 + ln) * 64];
            const int sw = (ln & 7) << 1;
            #pragma unroll
            for (int k2 = 0; k2 < 2; ++k2) {
                ushort4 lo4 = *(const ushort4*)&row[((k2 * 8 + hi)     ^ sw) * 4];
                ushort4 hi4 = *(const ushort4*)&row[((k2 * 8 + hi + 4) ^ sw) * 4];
                bf16x8 va;
                va[0] = (short)lo4.x; va[1] = (short)lo4.y; va[2] = (short)lo4.z; va[3] = (short)lo4.w;
                va[4] = (short)hi4.x; va[5] = (short)hi4.y; va[6] = (short)hi4.z; va[7] = (short)hi4.w;
                o[dt] = MFMA16(va, pa[k2], o[dt]);
            }
        }
    }

    // epilogue: lane owns qrow; d = dt*16 + hi*4 + r
    float inv = 1.f / l_run;
    #pragma unroll
    for (int dt = 0; dt < 4; ++dt) {
        ushort4 ov;
        ov.x = f2bf(o[dt][0] * inv);
        ov.y = f2bf(o[dt][1] * inv);
        ov.z = f2bf(o[dt][2] * inv);
        ov.w = f2bf(o[dt][3] * inv);
        *(ushort4*)&ctx[(tok + qrow) * 1024 + h * 64 + dt * 16 + hi * 4] = ov;
    }
}

extern "C" void kernel_launch(void* const* d_in, const int* in_sizes, int n_in,
                              void* d_out, int out_size, void* d_ws, size_t ws_size,
                              hipStream_t stream) {
    const float* hs     = (const float*)d_in[0];   // [2,2048,1024]
    const float* w_attn = (const float*)d_in[1];   // [1024,3072]
    const float* b_attn = (const float*)d_in[2];   // [3072]
    const float* w_proj = (const float*)d_in[3];   // [1024,1024]
    const float* b_proj = (const float*)d_in[4];   // [1024]
    float* out = (float*)d_out;                    // [2,2048,1024] fp32

    char* ws = (char*)d_ws;
    u16* hsb  = (u16*)ws;                          // 8 MB
    u16* waT  = (u16*)(ws + ((size_t)8  << 20));   // 6 MB  [3072][1024]
    u16* wpT  = (u16*)(ws + ((size_t)14 << 20));   // 2 MB  [1024][1024]
    u16* qkvb = (u16*)(ws + ((size_t)16 << 20));   // 24 MB [4096][3072]
    u16* ctxb = (u16*)(ws + ((size_t)40 << 20));   // 8 MB  [4096][1024]
    u16* vtg  = (u16*)(ws + ((size_t)48 << 20));   // 8 MB  [32*64][2048]

    cast_bf16<<<4096, 256, 0, stream>>>(hs, hsb, NT * 1024);
    transpose_cast<<<dim3(16, 48), 256, 0, stream>>>(w_attn, waT, 3072);
    transpose_cast<<<dim3(16, 16), 256, 0, stream>>>(w_proj, wpT, 1024);

    gemm_bt<3072, u16><<<dim3(NT / 128, 3072 / 128), 256, 0, stream>>>(hsb, waT, b_attn, qkvb);
    transpose_v<<<dim3(BB * 16, SS / 64), 256, 0, stream>>>(qkvb, vtg);
    attn_mfma<<<dim3(BB * 16, SS / 64), 256, 0, stream>>>(qkvb, vtg, ctxb);
    gemm_bt<1024, float><<<dim3(NT / 128, 1024 / 128), 256, 0, stream>>>(ctxb, wpT, b_proj, out);
}

// Round 7
// 118.793 us; speedup vs baseline: 1.0011x; 1.0011x over previous
//
#include <hip/hip_runtime.h>
#include <hip/hip_bf16.h>
#include <math.h>
#include <stdint.h>

typedef unsigned short u16;
typedef __attribute__((ext_vector_type(8))) short bf16x8;
typedef __attribute__((ext_vector_type(4))) float f32x4;

#define MFMA16(A,B,C) __builtin_amdgcn_mfma_f32_16x16x32_bf16(A,B,C,0,0,0)

#define BB 2
#define SS 2048
#define NT (BB*SS)

__device__ __forceinline__ u16 f2bf(float f) {
    union { float f; unsigned u; } c; c.f = f;
    unsigned r = c.u + 0x7FFF + ((c.u >> 16) & 1);
    return (u16)(r >> 16);
}
__device__ __forceinline__ float bf2f(u16 v) {
    union { unsigned u; float f; } c; c.u = ((unsigned)v) << 16;
    return c.f;
}

// async global->LDS, 16B per lane. LDS dest = wave-uniform base + lane*16B.
__device__ __forceinline__ void gl_lds16(const u16* g, u16* l) {
    __builtin_amdgcn_global_load_lds(
        (const __attribute__((address_space(1))) void*)(uintptr_t)g,
        (__attribute__((address_space(3))) void*)(uintptr_t)l, 16, 0, 0);
}

// ---------------- fp32 -> bf16 elementwise cast
__global__ __launch_bounds__(256) void cast_bf16(const float* __restrict__ in,
                                                 u16* __restrict__ out, int n) {
    int i = (blockIdx.x * 256 + threadIdx.x) * 4;
    if (i < n) {
        float4 v = *(const float4*)&in[i];
        ushort4 o;
        o.x = f2bf(v.x); o.y = f2bf(v.y); o.z = f2bf(v.z); o.w = f2bf(v.w);
        *(ushort4*)&out[i] = o;
    }
}

// ---------------- fp32 [1024][M] -> bf16 transposed [M][1024]
__global__ __launch_bounds__(256) void transpose_cast(const float* __restrict__ in,
                                                      u16* __restrict__ out, int M) {
    __shared__ float tile[64][65];
    const int k0 = blockIdx.x * 64, m0 = blockIdx.y * 64;
    const int t = threadIdx.x;
    #pragma unroll
    for (int rep = 0; rep < 16; ++rep) {
        int idx = rep * 256 + t;
        int kk = idx >> 6, mm = idx & 63;
        tile[kk][mm] = in[(size_t)(k0 + kk) * M + m0 + mm];
    }
    __syncthreads();
    #pragma unroll
    for (int rep = 0; rep < 16; ++rep) {
        int idx = rep * 256 + t;
        int mm = idx >> 6, kk = idx & 63;
        out[(size_t)(m0 + mm) * 1024 + k0 + kk] = f2bf(tile[kk][mm]);
    }
}

// ---------------- V pre-transpose: qkvb V-part [token][h*64+d] -> vtg[bh*64+d][token]
// grid (32 bh, 32 token-tiles); plain (unswizzled) output layout.
__global__ __launch_bounds__(256) void transpose_v(const u16* __restrict__ qkvb,
                                                   u16* __restrict__ vtg) {
    __shared__ u16 tile[64][72];   // [token][d], 16B-aligned rows
    const int bh = blockIdx.x, kt = blockIdx.y;
    const int b = bh >> 4, h = bh & 15;
    const int t = threadIdx.x;
    const int tt = t >> 2;
    #pragma unroll
    for (int r = 0; r < 2; ++r) {
        int c = (t & 3) + r * 4;   // 16B chunk of the 64-d row
        *(bf16x8*)&tile[tt][c * 8] =
            *(const bf16x8*)&qkvb[(size_t)(b * SS + kt * 64 + tt) * 3072 + 2048 + h * 64 + c * 8];
    }
    __syncthreads();
    const int d = t >> 2;
    #pragma unroll
    for (int r = 0; r < 2; ++r) {
        int c16 = (t & 3) + r * 4;  // out 16B chunk = tokens c16*8..+7
        ushort4 o0, o1;
        o0.x = tile[c16 * 8 + 0][d]; o0.y = tile[c16 * 8 + 1][d];
        o0.z = tile[c16 * 8 + 2][d]; o0.w = tile[c16 * 8 + 3][d];
        o1.x = tile[c16 * 8 + 4][d]; o1.y = tile[c16 * 8 + 5][d];
        o1.z = tile[c16 * 8 + 6][d]; o1.w = tile[c16 * 8 + 7][d];
        u16* dst = &vtg[(size_t)(bh * 64 + d) * SS + kt * 64 + c16 * 8];
        *(ushort4*)dst = o0;
        *(ushort4*)(dst + 4) = o1;
    }
}

// ---------------- bf16 MFMA GEMM with global_load_lds staging (m97 pattern)
template<int MD, typename OutT>
__global__ __launch_bounds__(256) void gemm_bt(const u16* __restrict__ A,
                                               const u16* __restrict__ BT,
                                               const float* __restrict__ bias,
                                               OutT* __restrict__ C) {
    __shared__ u16 As[128 * 32];
    __shared__ u16 Bs[128 * 32];
    const int t = threadIdx.x;
    const int lane = t & 63;
    const int w = t >> 6;
    const int wr = (w >> 1) * 64, wc = (w & 1) * 64;
    const int ln = lane & 15, hi = lane >> 4;
    const int n0 = blockIdx.x * 128;
    const int m0 = blockIdx.y * 128;

    f32x4 acc[4][4];
    const f32x4 fz = {0.f, 0.f, 0.f, 0.f};
    #pragma unroll
    for (int i = 0; i < 4; ++i)
        #pragma unroll
        for (int j = 0; j < 4; ++j) acc[i][j] = fz;

    const int srow_in = lane >> 2;
    const int schunk  = lane & 3;

    for (int k0 = 0; k0 < 1024; k0 += 32) {
        __syncthreads();
        #pragma unroll
        for (int p = 0; p < 2; ++p) {
            int q   = w * 2 + p;
            int row = q * 16 + srow_in;
            int cg  = schunk ^ (row & 3);
            gl_lds16(&A [(size_t)(n0 + row) * 1024 + k0 + cg * 8], &As[q * 512]);
            gl_lds16(&BT[(size_t)(m0 + row) * 1024 + k0 + cg * 8], &Bs[q * 512]);
        }
        __syncthreads();
        bf16x8 af[4], bf[4];
        #pragma unroll
        for (int mi = 0; mi < 4; ++mi) {
            int r = wr + mi * 16 + ln;
            af[mi] = *(const bf16x8*)&As[r * 32 + ((hi ^ (r & 3)) << 3)];
        }
        #pragma unroll
        for (int ni = 0; ni < 4; ++ni) {
            int r = wc + ni * 16 + ln;
            bf[ni] = *(const bf16x8*)&Bs[r * 32 + ((hi ^ (r & 3)) << 3)];
        }
        #pragma unroll
        for (int mi = 0; mi < 4; ++mi)
            #pragma unroll
            for (int ni = 0; ni < 4; ++ni)
                acc[mi][ni] = MFMA16(af[mi], bf[ni], acc[mi][ni]);
    }

    #pragma unroll
    for (int mi = 0; mi < 4; ++mi) {
        #pragma unroll
        for (int ni = 0; ni < 4; ++ni) {
            int col = m0 + wc + ni * 16 + ln;
            float bv = bias[col];
            #pragma unroll
            for (int r = 0; r < 4; ++r) {
                int row = n0 + wr + mi * 16 + hi * 4 + r;
                float v = acc[mi][ni][r] + bv;
                if constexpr (sizeof(OutT) == 4) C[(size_t)row * MD + col] = v;
                else                             C[(size_t)row * MD + col] = (OutT)f2bf(v);
            }
        }
    }
}

// ---------------- MFMA flash attention (bf16), fully DMA-staged K and V^T,
// 2-phase double buffer (issue next-tile DMA before compute; __syncthreads'
// vmcnt(0)+barrier drains it after compute).
__global__ __launch_bounds__(256) void attn_mfma(const u16* __restrict__ qkv,
                                                 const u16* __restrict__ vtg,
                                                 u16* __restrict__ ctx) {
    __shared__ u16 Ks[2][64 * 64];  // [key][8B chunk c], c holds global c^(key&7) (8B units via 16B DMA)
    __shared__ u16 Vs[2][64 * 64];  // [d][8B chunk p], p holds src 8B chunk p^((d&7)<<1)
    const int bh = blockIdx.x;
    const int qt = 31 - blockIdx.y;          // longest-first (LPT)
    const int b = bh >> 4, h = bh & 15;
    const int t = threadIdx.x, w = t >> 6, lane = t & 63;
    const int ln = lane & 15, hi = lane >> 4;
    const int qrow = qt * 64 + w * 16 + ln;
    const size_t tok = (size_t)b * SS;

    // Q fragment (B operand of S^T): k = t2*32 + hi*8 + i, scaled by 1/8
    bf16x8 qb[2];
    #pragma unroll
    for (int t2 = 0; t2 < 2; ++t2) {
        bf16x8 v = *(const bf16x8*)&qkv[(tok + qrow) * 3072 + h * 64 + t2 * 32 + hi * 8];
        #pragma unroll
        for (int i = 0; i < 8; ++i)
            v[i] = (short)f2bf(bf2f((u16)v[i]) * 0.125f);
        qb[t2] = v;
    }

    float m_run = -1e30f, l_run = 0.f;
    f32x4 o[4];
    const f32x4 fz = {0.f, 0.f, 0.f, 0.f};
    #pragma unroll
    for (int i = 0; i < 4; ++i) o[i] = fz;

    // staging lane maps
    const int kkey_l = w * 8 + (lane >> 3);            // K row, + p*32
    const int ksch   = lane & 7;                        // K 16B chunk
    const int vrow_l = lane >> 3;                       // V row within 8-group
    const int vsch   = (lane & 7) ^ (lane >> 3);        // pre-swizzled V src 16B chunk

    const size_t vbase = (size_t)bh * 64 * SS;

    // prologue: stage tile 0 into buffer 0
    {
        const size_t kvb = (tok /*+ 0*/) * 3072 + h * 64;
        #pragma unroll
        for (int p = 0; p < 2; ++p) {
            int kk = p * 32 + kkey_l;
            gl_lds16(&qkv[kvb + (size_t)kk * 3072 + 1024 + ((ksch ^ (kk & 7)) << 3)],
                     &Ks[0][(p * 32 + w * 8) * 64]);
            int d = w * 16 + p * 8 + vrow_l;
            gl_lds16(&vtg[vbase + (size_t)d * SS + (vsch << 3)],
                     &Vs[0][(w * 16 + p * 8) * 64]);
        }
    }

    for (int kt = 0; kt <= qt; ++kt) {
        const int cur = kt & 1;
        __syncthreads();   // drains DMA for buf[cur] (vmcnt0 before barrier) + syncs readers

        if (kt < qt) {     // issue next-tile DMA into the other buffer
            const int nxt = cur ^ 1;
            const size_t kvb = (tok + (kt + 1) * 64) * 3072 + h * 64;
            #pragma unroll
            for (int p = 0; p < 2; ++p) {
                int kk = p * 32 + kkey_l;
                gl_lds16(&qkv[kvb + (size_t)kk * 3072 + 1024 + ((ksch ^ (kk & 7)) << 3)],
                         &Ks[nxt][(p * 32 + w * 8) * 64]);
                int d = w * 16 + p * 8 + vrow_l;
                gl_lds16(&vtg[vbase + (size_t)d * SS + (kt + 1) * 64 + (vsch << 3)],
                         &Vs[nxt][(w * 16 + p * 8) * 64]);
            }
        }

        // S^T = K . Q^T : 4 key sub-tiles of 16
        f32x4 sacc[4];
        #pragma unroll
        for (int s = 0; s < 4; ++s) {
            int key = s * 16 + ln;
            f32x4 a = fz;
            #pragma unroll
            for (int t2 = 0; t2 < 2; ++t2) {
                bf16x8 kf = *(const bf16x8*)&Ks[cur][key * 64 + (((t2 * 4 + hi) ^ (key & 7)) << 3)];
                a = MFMA16(kf, qb[t2], a);
            }
            sacc[s] = a;
        }

        // online softmax (lane owns one q-row; reduce over hi via 2 shfls)
        float p_[16];
        float mloc = -1e30f;
        if (kt == qt) {
            #pragma unroll
            for (int s = 0; s < 4; ++s)
                #pragma unroll
                for (int r = 0; r < 4; ++r) {
                    int keyg = kt * 64 + s * 16 + hi * 4 + r;
                    float v = (keyg <= qrow) ? sacc[s][r] : -1e30f;
                    p_[s * 4 + r] = v;
                    mloc = fmaxf(mloc, v);
                }
        } else {
            #pragma unroll
            for (int s = 0; s < 4; ++s)
                #pragma unroll
                for (int r = 0; r < 4; ++r) {
                    float v = sacc[s][r];
                    p_[s * 4 + r] = v;
                    mloc = fmaxf(mloc, v);
                }
        }
        mloc = fmaxf(mloc, __shfl_xor(mloc, 16));
        mloc = fmaxf(mloc, __shfl_xor(mloc, 32));
        float m_new = fmaxf(m_run, mloc);
        float alpha = __expf(m_run - m_new);
        float lsum = 0.f;
        #pragma unroll
        for (int i = 0; i < 16; ++i) {
            float e = __expf(p_[i] - m_new);
            p_[i] = e;
            lsum += e;
        }
        lsum += __shfl_xor(lsum, 16);
        lsum += __shfl_xor(lsum, 32);
        l_run = l_run * alpha + lsum;
        m_run = m_new;
        #pragma unroll
        for (int dt = 0; dt < 4; ++dt) o[dt] *= alpha;

        // P -> bf16 fragments via packed convert (identity key bijection)
        bf16x8 pa[2];
        #pragma unroll
        for (int k2 = 0; k2 < 2; ++k2) {
            union { unsigned wd[4]; bf16x8 v; } pu;
            #pragma unroll
            for (int qi = 0; qi < 4; ++qi)
                asm("v_cvt_pk_bf16_f32 %0, %1, %2"
                    : "=v"(pu.wd[qi])
                    : "v"(p_[k2 * 8 + 2 * qi]), "v"(p_[k2 * 8 + 2 * qi + 1]));
            pa[k2] = pu.v;
        }

        // O^T += V^T . P^T ; va slot i = V[key k2*32+16*(i>>2)+hi*4+(i&3)][d]
        #pragma unroll
        for (int dt = 0; dt < 4; ++dt) {
            const u16* row = &Vs[cur][(dt * 16 + ln) * 64];
            const int sw = (ln & 7) << 1;
            #pragma unroll
            for (int k2 = 0; k2 < 2; ++k2) {
                ushort4 lo4 = *(const ushort4*)&row[((k2 * 8 + hi)     ^ sw) * 4];
                ushort4 hi4 = *(const ushort4*)&row[((k2 * 8 + hi + 4) ^ sw) * 4];
                bf16x8 va;
                va[0] = (short)lo4.x; va[1] = (short)lo4.y; va[2] = (short)lo4.z; va[3] = (short)lo4.w;
                va[4] = (short)hi4.x; va[5] = (short)hi4.y; va[6] = (short)hi4.z; va[7] = (short)hi4.w;
                o[dt] = MFMA16(va, pa[k2], o[dt]);
            }
        }
    }

    // epilogue: lane owns qrow; d = dt*16 + hi*4 + r
    float inv = 1.f / l_run;
    #pragma unroll
    for (int dt = 0; dt < 4; ++dt) {
        ushort4 ov;
        ov.x = f2bf(o[dt][0] * inv);
        ov.y = f2bf(o[dt][1] * inv);
        ov.z = f2bf(o[dt][2] * inv);
        ov.w = f2bf(o[dt][3] * inv);
        *(ushort4*)&ctx[(tok + qrow) * 1024 + h * 64 + dt * 16 + hi * 4] = ov;
    }
}

extern "C" void kernel_launch(void* const* d_in, const int* in_sizes, int n_in,
                              void* d_out, int out_size, void* d_ws, size_t ws_size,
                              hipStream_t stream) {
    const float* hs     = (const float*)d_in[0];   // [2,2048,1024]
    const float* w_attn = (const float*)d_in[1];   // [1024,3072]
    const float* b_attn = (const float*)d_in[2];   // [3072]
    const float* w_proj = (const float*)d_in[3];   // [1024,1024]
    const float* b_proj = (const float*)d_in[4];   // [1024]
    float* out = (float*)d_out;                    // [2,2048,1024] fp32

    char* ws = (char*)d_ws;
    u16* hsb  = (u16*)ws;                          // 8 MB
    u16* waT  = (u16*)(ws + ((size_t)8  << 20));   // 6 MB  [3072][1024]
    u16* wpT  = (u16*)(ws + ((size_t)14 << 20));   // 2 MB  [1024][1024]
    u16* qkvb = (u16*)(ws + ((size_t)16 << 20));   // 24 MB [4096][3072]
    u16* ctxb = (u16*)(ws + ((size_t)40 << 20));   // 8 MB  [4096][1024]
    u16* vtg  = (u16*)(ws + ((size_t)48 << 20));   // 8 MB  [32*64][2048]

    cast_bf16<<<4096, 256, 0, stream>>>(hs, hsb, NT * 1024);
    transpose_cast<<<dim3(16, 48), 256, 0, stream>>>(w_attn, waT, 3072);
    transpose_cast<<<dim3(16, 16), 256, 0, stream>>>(w_proj, wpT, 1024);

    gemm_bt<3072, u16><<<dim3(NT / 128, 3072 / 128), 256, 0, stream>>>(hsb, waT, b_attn, qkvb);
    transpose_v<<<dim3(BB * 16, SS / 64), 256, 0, stream>>>(qkvb, vtg);
    attn_mfma<<<dim3(BB * 16, SS / 64), 256, 0, stream>>>(qkvb, vtg, ctxb);
    gemm_bt<1024, float><<<dim3(NT / 128, 1024 / 128), 256, 0, stream>>>(ctxb, wpT, b_proj, out);
}

// Round 8
// 118.405 us; speedup vs baseline: 1.0044x; 1.0033x over previous
//
#include <hip/hip_runtime.h>
#include <hip/hip_bf16.h>
#include <math.h>
#include <stdint.h>

typedef unsigned short u16;
typedef __attribute__((ext_vector_type(8))) short bf16x8;
typedef __attribute__((ext_vector_type(4))) float f32x4;

#define MFMA16(A,B,C) __builtin_amdgcn_mfma_f32_16x16x32_bf16(A,B,C,0,0,0)

#define BB 2
#define SS 2048
#define NT (BB*SS)

__device__ __forceinline__ u16 f2bf(float f) {
    union { float f; unsigned u; } c; c.f = f;
    unsigned r = c.u + 0x7FFF + ((c.u >> 16) & 1);
    return (u16)(r >> 16);
}
__device__ __forceinline__ float bf2f(u16 v) {
    union { unsigned u; float f; } c; c.u = ((unsigned)v) << 16;
    return c.f;
}

// async global->LDS, 16B per lane. LDS dest = wave-uniform base + lane*16B.
__device__ __forceinline__ void gl_lds16(const u16* g, u16* l) {
    __builtin_amdgcn_global_load_lds(
        (const __attribute__((address_space(1))) void*)(uintptr_t)g,
        (__attribute__((address_space(3))) void*)(uintptr_t)l, 16, 0, 0);
}

// ---------------- fp32 -> bf16 elementwise cast
__global__ __launch_bounds__(256) void cast_bf16(const float* __restrict__ in,
                                                 u16* __restrict__ out, int n) {
    int i = (blockIdx.x * 256 + threadIdx.x) * 4;
    if (i < n) {
        float4 v = *(const float4*)&in[i];
        ushort4 o;
        o.x = f2bf(v.x); o.y = f2bf(v.y); o.z = f2bf(v.z); o.w = f2bf(v.w);
        *(ushort4*)&out[i] = o;
    }
}

// ---------------- fp32 [1024][M] -> bf16 transposed [M][1024]
__global__ __launch_bounds__(256) void transpose_cast(const float* __restrict__ in,
                                                      u16* __restrict__ out, int M) {
    __shared__ float tile[64][65];
    const int k0 = blockIdx.x * 64, m0 = blockIdx.y * 64;
    const int t = threadIdx.x;
    #pragma unroll
    for (int rep = 0; rep < 16; ++rep) {
        int idx = rep * 256 + t;
        int kk = idx >> 6, mm = idx & 63;
        tile[kk][mm] = in[(size_t)(k0 + kk) * M + m0 + mm];
    }
    __syncthreads();
    #pragma unroll
    for (int rep = 0; rep < 16; ++rep) {
        int idx = rep * 256 + t;
        int mm = idx >> 6, kk = idx & 63;
        out[(size_t)(m0 + mm) * 1024 + k0 + kk] = f2bf(tile[kk][mm]);
    }
}

// ---------------- V pre-transpose: qkvb V-part [token][h*64+d] -> vtg[bh*64+d][token]
// grid (32 bh, 32 token-tiles); plain (unswizzled) output layout.
__global__ __launch_bounds__(256) void transpose_v(const u16* __restrict__ qkvb,
                                                   u16* __restrict__ vtg) {
    __shared__ u16 tile[64][72];   // [token][d], 16B-aligned rows
    const int bh = blockIdx.x, kt = blockIdx.y;
    const int b = bh >> 4, h = bh & 15;
    const int t = threadIdx.x;
    const int tt = t >> 2;
    #pragma unroll
    for (int r = 0; r < 2; ++r) {
        int c = (t & 3) + r * 4;   // 16B chunk of the 64-d row
        *(bf16x8*)&tile[tt][c * 8] =
            *(const bf16x8*)&qkvb[(size_t)(b * SS + kt * 64 + tt) * 3072 + 2048 + h * 64 + c * 8];
    }
    __syncthreads();
    const int d = t >> 2;
    #pragma unroll
    for (int r = 0; r < 2; ++r) {
        int c16 = (t & 3) + r * 4;  // out 16B chunk = tokens c16*8..+7
        ushort4 o0, o1;
        o0.x = tile[c16 * 8 + 0][d]; o0.y = tile[c16 * 8 + 1][d];
        o0.z = tile[c16 * 8 + 2][d]; o0.w = tile[c16 * 8 + 3][d];
        o1.x = tile[c16 * 8 + 4][d]; o1.y = tile[c16 * 8 + 5][d];
        o1.z = tile[c16 * 8 + 6][d]; o1.w = tile[c16 * 8 + 7][d];
        u16* dst = &vtg[(size_t)(bh * 64 + d) * SS + kt * 64 + c16 * 8];
        *(ushort4*)dst = o0;
        *(ushort4*)(dst + 4) = o1;
    }
}

// ---------------- bf16 MFMA GEMM with global_load_lds staging (m97 pattern)
template<int MD, typename OutT>
__global__ __launch_bounds__(256) void gemm_bt(const u16* __restrict__ A,
                                               const u16* __restrict__ BT,
                                               const float* __restrict__ bias,
                                               OutT* __restrict__ C) {
    __shared__ u16 As[128 * 32];
    __shared__ u16 Bs[128 * 32];
    const int t = threadIdx.x;
    const int lane = t & 63;
    const int w = t >> 6;
    const int wr = (w >> 1) * 64, wc = (w & 1) * 64;
    const int ln = lane & 15, hi = lane >> 4;
    const int n0 = blockIdx.x * 128;
    const int m0 = blockIdx.y * 128;

    f32x4 acc[4][4];
    const f32x4 fz = {0.f, 0.f, 0.f, 0.f};
    #pragma unroll
    for (int i = 0; i < 4; ++i)
        #pragma unroll
        for (int j = 0; j < 4; ++j) acc[i][j] = fz;

    const int srow_in = lane >> 2;
    const int schunk  = lane & 3;

    for (int k0 = 0; k0 < 1024; k0 += 32) {
        __syncthreads();
        #pragma unroll
        for (int p = 0; p < 2; ++p) {
            int q   = w * 2 + p;
            int row = q * 16 + srow_in;
            int cg  = schunk ^ (row & 3);
            gl_lds16(&A [(size_t)(n0 + row) * 1024 + k0 + cg * 8], &As[q * 512]);
            gl_lds16(&BT[(size_t)(m0 + row) * 1024 + k0 + cg * 8], &Bs[q * 512]);
        }
        __syncthreads();
        bf16x8 af[4], bf[4];
        #pragma unroll
        for (int mi = 0; mi < 4; ++mi) {
            int r = wr + mi * 16 + ln;
            af[mi] = *(const bf16x8*)&As[r * 32 + ((hi ^ (r & 3)) << 3)];
        }
        #pragma unroll
        for (int ni = 0; ni < 4; ++ni) {
            int r = wc + ni * 16 + ln;
            bf[ni] = *(const bf16x8*)&Bs[r * 32 + ((hi ^ (r & 3)) << 3)];
        }
        #pragma unroll
        for (int mi = 0; mi < 4; ++mi)
            #pragma unroll
            for (int ni = 0; ni < 4; ++ni)
                acc[mi][ni] = MFMA16(af[mi], bf[ni], acc[mi][ni]);
    }

    #pragma unroll
    for (int mi = 0; mi < 4; ++mi) {
        #pragma unroll
        for (int ni = 0; ni < 4; ++ni) {
            int col = m0 + wc + ni * 16 + ln;
            float bv = bias[col];
            #pragma unroll
            for (int r = 0; r < 4; ++r) {
                int row = n0 + wr + mi * 16 + hi * 4 + r;
                float v = acc[mi][ni][r] + bv;
                if constexpr (sizeof(OutT) == 4) C[(size_t)row * MD + col] = v;
                else                             C[(size_t)row * MD + col] = (OutT)f2bf(v);
            }
        }
    }
}

// ---------------- MFMA flash attention (bf16), fully DMA-staged K and V^T,
// 2-phase double buffer (issue next-tile DMA before compute; __syncthreads'
// vmcnt(0)+barrier drains it after compute).
__global__ __launch_bounds__(256) void attn_mfma(const u16* __restrict__ qkv,
                                                 const u16* __restrict__ vtg,
                                                 u16* __restrict__ ctx) {
    __shared__ u16 Ks[2][64 * 64];  // [key][8B chunk c], c holds global c^(key&7) (8B units via 16B DMA)
    __shared__ u16 Vs[2][64 * 64];  // [d][8B chunk p], p holds src 8B chunk p^((d&7)<<1)
    const int bh = blockIdx.x;
    const int qt = 31 - blockIdx.y;          // longest-first (LPT)
    const int b = bh >> 4, h = bh & 15;
    const int t = threadIdx.x, w = t >> 6, lane = t & 63;
    const int ln = lane & 15, hi = lane >> 4;
    const int qrow = qt * 64 + w * 16 + ln;
    const size_t tok = (size_t)b * SS;

    // Q fragment (B operand of S^T): k = t2*32 + hi*8 + i, scaled by 1/8
    bf16x8 qb[2];
    #pragma unroll
    for (int t2 = 0; t2 < 2; ++t2) {
        bf16x8 v = *(const bf16x8*)&qkv[(tok + qrow) * 3072 + h * 64 + t2 * 32 + hi * 8];
        #pragma unroll
        for (int i = 0; i < 8; ++i)
            v[i] = (short)f2bf(bf2f((u16)v[i]) * 0.125f);
        qb[t2] = v;
    }

    float m_run = -1e30f, l_run = 0.f;
    f32x4 o[4];
    const f32x4 fz = {0.f, 0.f, 0.f, 0.f};
    #pragma unroll
    for (int i = 0; i < 4; ++i) o[i] = fz;

    // staging lane maps
    const int kkey_l = w * 8 + (lane >> 3);            // K row, + p*32
    const int ksch   = lane & 7;                        // K 16B chunk
    const int vrow_l = lane >> 3;                       // V row within 8-group
    const int vsch   = (lane & 7) ^ (lane >> 3);        // pre-swizzled V src 16B chunk

    const size_t vbase = (size_t)bh * 64 * SS;

    // prologue: stage tile 0 into buffer 0
    {
        const size_t kvb = (tok /*+ 0*/) * 3072 + h * 64;
        #pragma unroll
        for (int p = 0; p < 2; ++p) {
            int kk = p * 32 + kkey_l;
            gl_lds16(&qkv[kvb + (size_t)kk * 3072 + 1024 + ((ksch ^ (kk & 7)) << 3)],
                     &Ks[0][(p * 32 + w * 8) * 64]);
            int d = w * 16 + p * 8 + vrow_l;
            gl_lds16(&vtg[vbase + (size_t)d * SS + (vsch << 3)],
                     &Vs[0][(w * 16 + p * 8) * 64]);
        }
    }

    for (int kt = 0; kt <= qt; ++kt) {
        const int cur = kt & 1;
        __syncthreads();   // drains DMA for buf[cur] (vmcnt0 before barrier) + syncs readers

        if (kt < qt) {     // issue next-tile DMA into the other buffer
            const int nxt = cur ^ 1;
            const size_t kvb = (tok + (kt + 1) * 64) * 3072 + h * 64;
            #pragma unroll
            for (int p = 0; p < 2; ++p) {
                int kk = p * 32 + kkey_l;
                gl_lds16(&qkv[kvb + (size_t)kk * 3072 + 1024 + ((ksch ^ (kk & 7)) << 3)],
                         &Ks[nxt][(p * 32 + w * 8) * 64]);
                int d = w * 16 + p * 8 + vrow_l;
                gl_lds16(&vtg[vbase + (size_t)d * SS + (kt + 1) * 64 + (vsch << 3)],
                         &Vs[nxt][(w * 16 + p * 8) * 64]);
            }
        }

        // S^T = K . Q^T : 4 key sub-tiles of 16
        f32x4 sacc[4];
        #pragma unroll
        for (int s = 0; s < 4; ++s) {
            int key = s * 16 + ln;
            f32x4 a = fz;
            #pragma unroll
            for (int t2 = 0; t2 < 2; ++t2) {
                bf16x8 kf = *(const bf16x8*)&Ks[cur][key * 64 + (((t2 * 4 + hi) ^ (key & 7)) << 3)];
                a = MFMA16(kf, qb[t2], a);
            }
            sacc[s] = a;
        }

        // online softmax (lane owns one q-row; reduce over hi via 2 shfls)
        float p_[16];
        float mloc = -1e30f;
        if (kt == qt) {
            #pragma unroll
            for (int s = 0; s < 4; ++s)
                #pragma unroll
                for (int r = 0; r < 4; ++r) {
                    int keyg = kt * 64 + s * 16 + hi * 4 + r;
                    float v = (keyg <= qrow) ? sacc[s][r] : -1e30f;
                    p_[s * 4 + r] = v;
                    mloc = fmaxf(mloc, v);
                }
        } else {
            #pragma unroll
            for (int s = 0; s < 4; ++s)
                #pragma unroll
                for (int r = 0; r < 4; ++r) {
                    float v = sacc[s][r];
                    p_[s * 4 + r] = v;
                    mloc = fmaxf(mloc, v);
                }
        }
        mloc = fmaxf(mloc, __shfl_xor(mloc, 16));
        mloc = fmaxf(mloc, __shfl_xor(mloc, 32));
        float m_new = fmaxf(m_run, mloc);
        float alpha = __expf(m_run - m_new);
        float lsum = 0.f;
        #pragma unroll
        for (int i = 0; i < 16; ++i) {
            float e = __expf(p_[i] - m_new);
            p_[i] = e;
            lsum += e;
        }
        lsum += __shfl_xor(lsum, 16);
        lsum += __shfl_xor(lsum, 32);
        l_run = l_run * alpha + lsum;
        m_run = m_new;
        #pragma unroll
        for (int dt = 0; dt < 4; ++dt) o[dt] *= alpha;

        // P -> bf16 fragments via packed convert (identity key bijection)
        bf16x8 pa[2];
        #pragma unroll
        for (int k2 = 0; k2 < 2; ++k2) {
            union { unsigned wd[4]; bf16x8 v; } pu;
            #pragma unroll
            for (int qi = 0; qi < 4; ++qi)
                asm("v_cvt_pk_bf16_f32 %0, %1, %2"
                    : "=v"(pu.wd[qi])
                    : "v"(p_[k2 * 8 + 2 * qi]), "v"(p_[k2 * 8 + 2 * qi + 1]));
            pa[k2] = pu.v;
        }

        // O^T += V^T . P^T ; va slot i = V[key k2*32+16*(i>>2)+hi*4+(i&3)][d]
        #pragma unroll
        for (int dt = 0; dt < 4; ++dt) {
            const u16* row = &Vs[cur][(dt * 16 + ln) * 64];
            const int sw = (ln & 7) << 1;
            #pragma unroll
            for (int k2 = 0; k2 < 2; ++k2) {
                ushort4 lo4 = *(const ushort4*)&row[((k2 * 8 + hi)     ^ sw) * 4];
                ushort4 hi4 = *(const ushort4*)&row[((k2 * 8 + hi + 4) ^ sw) * 4];
                bf16x8 va;
                va[0] = (short)lo4.x; va[1] = (short)lo4.y; va[2] = (short)lo4.z; va[3] = (short)lo4.w;
                va[4] = (short)hi4.x; va[5] = (short)hi4.y; va[6] = (short)hi4.z; va[7] = (short)hi4.w;
                o[dt] = MFMA16(va, pa[k2], o[dt]);
            }
        }
    }

    // epilogue: lane owns qrow; d = dt*16 + hi*4 + r
    float inv = 1.f / l_run;
    #pragma unroll
    for (int dt = 0; dt < 4; ++dt) {
        ushort4 ov;
        ov.x = f2bf(o[dt][0] * inv);
        ov.y = f2bf(o[dt][1] * inv);
        ov.z = f2bf(o[dt][2] * inv);
        ov.w = f2bf(o[dt][3] * inv);
        *(ushort4*)&ctx[(tok + qrow) * 1024 + h * 64 + dt * 16 + hi * 4] = ov;
    }
}

extern "C" void kernel_launch(void* const* d_in, const int* in_sizes, int n_in,
                              void* d_out, int out_size, void* d_ws, size_t ws_size,
                              hipStream_t stream) {
    const float* hs     = (const float*)d_in[0];   // [2,2048,1024]
    const float* w_attn = (const float*)d_in[1];   // [1024,3072]
    const float* b_attn = (const float*)d_in[2];   // [3072]
    const float* w_proj = (const float*)d_in[3];   // [1024,1024]
    const float* b_proj = (const float*)d_in[4];   // [1024]
    float* out = (float*)d_out;                    // [2,2048,1024] fp32

    char* ws = (char*)d_ws;
    u16* hsb  = (u16*)ws;                          // 8 MB
    u16* waT  = (u16*)(ws + ((size_t)8  << 20));   // 6 MB  [3072][1024]
    u16* wpT  = (u16*)(ws + ((size_t)14 << 20));   // 2 MB  [1024][1024]
    u16* qkvb = (u16*)(ws + ((size_t)16 << 20));   // 24 MB [4096][3072]
    u16* ctxb = (u16*)(ws + ((size_t)40 << 20));   // 8 MB  [4096][1024]
    u16* vtg  = (u16*)(ws + ((size_t)48 << 20));   // 8 MB  [32*64][2048]

    cast_bf16<<<4096, 256, 0, stream>>>(hs, hsb, NT * 1024);
    transpose_cast<<<dim3(16, 48), 256, 0, stream>>>(w_attn, waT, 3072);
    transpose_cast<<<dim3(16, 16), 256, 0, stream>>>(w_proj, wpT, 1024);

    gemm_bt<3072, u16><<<dim3(NT / 128, 3072 / 128), 256, 0, stream>>>(hsb, waT, b_attn, qkvb);
    transpose_v<<<dim3(BB * 16, SS / 64), 256, 0, stream>>>(qkvb, vtg);
    attn_mfma<<<dim3(BB * 16, SS / 64), 256, 0, stream>>>(qkvb, vtg, ctxb);
    gemm_bt<1024, float><<<dim3(NT / 128, 1024 / 128), 256, 0, stream>>>(ctxb, wpT, b_proj, out);
}

// Round 10
// 111.265 us; speedup vs baseline: 1.0688x; 1.0642x over previous
//
#include <hip/hip_runtime.h>
#include <hip/hip_bf16.h>
#include <math.h>
#include <stdint.h>

typedef unsigned short u16;
typedef __attribute__((ext_vector_type(8))) short bf16x8;
typedef __attribute__((ext_vector_type(4))) float f32x4;

#define MFMA16(A,B,C) __builtin_amdgcn_mfma_f32_16x16x32_bf16(A,B,C,0,0,0)
#define EXP2F(x) __builtin_amdgcn_exp2f(x)

#define BB 2
#define SS 2048
#define NT (BB*SS)

__device__ __forceinline__ u16 f2bf(float f) {
    union { float f; unsigned u; } c; c.f = f;
    unsigned r = c.u + 0x7FFF + ((c.u >> 16) & 1);
    return (u16)(r >> 16);
}
__device__ __forceinline__ float bf2f(u16 v) {
    union { unsigned u; float f; } c; c.u = ((unsigned)v) << 16;
    return c.f;
}

// async global->LDS, 16B per lane. LDS dest = wave-uniform base + lane*16B.
__device__ __forceinline__ void gl_lds16(const u16* g, u16* l) {
    __builtin_amdgcn_global_load_lds(
        (const __attribute__((address_space(1))) void*)(uintptr_t)g,
        (__attribute__((address_space(3))) void*)(uintptr_t)l, 16, 0, 0);
}

// ---------------- fp32 -> bf16 elementwise cast
__global__ __launch_bounds__(256) void cast_bf16(const float* __restrict__ in,
                                                 u16* __restrict__ out, int n) {
    int i = (blockIdx.x * 256 + threadIdx.x) * 4;
    if (i < n) {
        float4 v = *(const float4*)&in[i];
        ushort4 o;
        o.x = f2bf(v.x); o.y = f2bf(v.y); o.z = f2bf(v.z); o.w = f2bf(v.w);
        *(ushort4*)&out[i] = o;
    }
}

// ---------------- fp32 [1024][M] -> bf16 transposed [M][1024]
__global__ __launch_bounds__(256) void transpose_cast(const float* __restrict__ in,
                                                      u16* __restrict__ out, int M) {
    __shared__ float tile[64][65];
    const int k0 = blockIdx.x * 64, m0 = blockIdx.y * 64;
    const int t = threadIdx.x;
    #pragma unroll
    for (int rep = 0; rep < 16; ++rep) {
        int idx = rep * 256 + t;
        int kk = idx >> 6, mm = idx & 63;
        tile[kk][mm] = in[(size_t)(k0 + kk) * M + m0 + mm];
    }
    __syncthreads();
    #pragma unroll
    for (int rep = 0; rep < 16; ++rep) {
        int idx = rep * 256 + t;
        int mm = idx >> 6, kk = idx & 63;
        out[(size_t)(m0 + mm) * 1024 + k0 + kk] = f2bf(tile[kk][mm]);
    }
}

// ---------------- V pre-transpose into BLOCKED layout
// vtg[(bh*32+kt)*4096 + (g*64+d)*8 .. +7] = 16B block:
//   { V[tok0..tok0+3][d], V[tok0+16..tok0+19][d] },  tok0 = (g>>2)*32 + (g&3)*4
// so attn's ds_read_b128 slot i = V[key 32*k2 + 16*(i>>2) + 4*hi + (i&3)][d]
// with g = k2*4 + hi  (matches the P-fragment key bijection exactly).
__global__ __launch_bounds__(256) void transpose_v(const u16* __restrict__ qkvb,
                                                   u16* __restrict__ vtg) {
    __shared__ u16 tile[64][72];   // [token][d]
    const int bh = blockIdx.x, kt = blockIdx.y;
    const int b = bh >> 4, h = bh & 15;
    const int t = threadIdx.x;
    const int tt = t >> 2;
    #pragma unroll
    for (int r = 0; r < 2; ++r) {
        int c = (t & 3) + r * 4;   // 16B chunk of the 64-d row
        *(bf16x8*)&tile[tt][c * 8] =
            *(const bf16x8*)&qkvb[(size_t)(b * SS + kt * 64 + tt) * 3072 + 2048 + h * 64 + c * 8];
    }
    __syncthreads();
    u16* dst0 = vtg + ((size_t)bh * 32 + kt) * 4096;
    #pragma unroll
    for (int rep = 0; rep < 2; ++rep) {
        int flat = rep * 256 + t;        // = g*64 + d
        int g = flat >> 6, d = flat & 63;
        int tok0 = (g >> 2) * 32 + (g & 3) * 4;
        ushort4 a, bb;
        a.x  = tile[tok0 + 0][d];  a.y  = tile[tok0 + 1][d];
        a.z  = tile[tok0 + 2][d];  a.w  = tile[tok0 + 3][d];
        bb.x = tile[tok0 + 16][d]; bb.y = tile[tok0 + 17][d];
        bb.z = tile[tok0 + 18][d]; bb.w = tile[tok0 + 19][d];
        u16* dst = dst0 + (size_t)flat * 8;
        *(ushort4*)dst = a;
        *(ushort4*)(dst + 4) = bb;
    }
}

// ---------------- bf16 MFMA GEMM with global_load_lds staging (m97 pattern)
template<int MD, typename OutT>
__global__ __launch_bounds__(256) void gemm_bt(const u16* __restrict__ A,
                                               const u16* __restrict__ BT,
                                               const float* __restrict__ bias,
                                               OutT* __restrict__ C) {
    __shared__ u16 As[128 * 32];
    __shared__ u16 Bs[128 * 32];
    const int t = threadIdx.x;
    const int lane = t & 63;
    const int w = t >> 6;
    const int wr = (w >> 1) * 64, wc = (w & 1) * 64;
    const int ln = lane & 15, hi = lane >> 4;
    const int n0 = blockIdx.x * 128;
    const int m0 = blockIdx.y * 128;

    f32x4 acc[4][4];
    const f32x4 fz = {0.f, 0.f, 0.f, 0.f};
    #pragma unroll
    for (int i = 0; i < 4; ++i)
        #pragma unroll
        for (int j = 0; j < 4; ++j) acc[i][j] = fz;

    const int srow_in = lane >> 2;
    const int schunk  = lane & 3;

    for (int k0 = 0; k0 < 1024; k0 += 32) {
        __syncthreads();
        #pragma unroll
        for (int p = 0; p < 2; ++p) {
            int q   = w * 2 + p;
            int row = q * 16 + srow_in;
            int cg  = schunk ^ (row & 3);
            gl_lds16(&A [(size_t)(n0 + row) * 1024 + k0 + cg * 8], &As[q * 512]);
            gl_lds16(&BT[(size_t)(m0 + row) * 1024 + k0 + cg * 8], &Bs[q * 512]);
        }
        __syncthreads();
        bf16x8 af[4], bf[4];
        #pragma unroll
        for (int mi = 0; mi < 4; ++mi) {
            int r = wr + mi * 16 + ln;
            af[mi] = *(const bf16x8*)&As[r * 32 + ((hi ^ (r & 3)) << 3)];
        }
        #pragma unroll
        for (int ni = 0; ni < 4; ++ni) {
            int r = wc + ni * 16 + ln;
            bf[ni] = *(const bf16x8*)&Bs[r * 32 + ((hi ^ (r & 3)) << 3)];
        }
        #pragma unroll
        for (int mi = 0; mi < 4; ++mi)
            #pragma unroll
            for (int ni = 0; ni < 4; ++ni)
                acc[mi][ni] = MFMA16(af[mi], bf[ni], acc[mi][ni]);
    }

    #pragma unroll
    for (int mi = 0; mi < 4; ++mi) {
        #pragma unroll
        for (int ni = 0; ni < 4; ++ni) {
            int col = m0 + wc + ni * 16 + ln;
            float bv = bias[col];
            #pragma unroll
            for (int r = 0; r < 4; ++r) {
                int row = n0 + wr + mi * 16 + hi * 4 + r;
                float v = acc[mi][ni][r] + bv;
                if constexpr (sizeof(OutT) == 4) C[(size_t)row * MD + col] = v;
                else                             C[(size_t)row * MD + col] = (OutT)f2bf(v);
            }
        }
    }
}

// ---------------- MFMA flash attention (bf16)
// K: gl_lds DMA, XOR-involution layout (round-4 proven).
// V: gl_lds DMA from blocked vtg -> single ds_read_b128 per (dt,k2).
// Softmax in exp2 domain (Q prescaled by 0.125*log2e), defer-max THR=8.
__global__ __launch_bounds__(256) void attn_mfma(const u16* __restrict__ qkv,
                                                 const u16* __restrict__ vtg,
                                                 u16* __restrict__ ctx) {
    __shared__ u16 Ks[2][64 * 64];  // [key][8B chunk c], c holds global c^(key&7)
    __shared__ u16 Vs[2][64 * 64];  // blocked: 16B block (g,d) at (g*64+d)*8
    const int bh = blockIdx.x;
    const int qt = 31 - blockIdx.y;          // longest-first (LPT)
    const int b = bh >> 4, h = bh & 15;
    const int t = threadIdx.x, w = t >> 6, lane = t & 63;
    const int ln = lane & 15, hi = lane >> 4;
    const int qrow = qt * 64 + w * 16 + ln;
    const size_t tok = (size_t)b * SS;

    // Q fragment (B operand of S^T), exp2 domain: scale = 0.125 * log2(e)
    bf16x8 qb[2];
    #pragma unroll
    for (int t2 = 0; t2 < 2; ++t2) {
        bf16x8 v = *(const bf16x8*)&qkv[(tok + qrow) * 3072 + h * 64 + t2 * 32 + hi * 8];
        #pragma unroll
        for (int i = 0; i < 8; ++i)
            v[i] = (short)f2bf(bf2f((u16)v[i]) * 0.180336881f);
        qb[t2] = v;
    }

    float m_run = -1e30f, l_run = 0.f;
    f32x4 o[4];
    const f32x4 fz = {0.f, 0.f, 0.f, 0.f};
    #pragma unroll
    for (int i = 0; i < 4; ++i) o[i] = fz;

    // staging lane maps
    const int kkey_l = w * 8 + (lane >> 3);   // K row, + p*32
    const int ksch   = lane & 7;              // K 16B chunk
    const u16* vsrc  = vtg + ((size_t)bh * 32) * 4096;

    // prologue: stage tile 0 into buffer 0
    {
        const size_t kvb = tok * 3072 + h * 64;
        #pragma unroll
        for (int p = 0; p < 2; ++p) {
            int kk = p * 32 + kkey_l;
            gl_lds16(&qkv[kvb + (size_t)kk * 3072 + 1024 + ((ksch ^ (kk & 7)) << 3)],
                     &Ks[0][(p * 32 + w * 8) * 64]);
            gl_lds16(&vsrc[(size_t)((w * 2 + p) * 64 + lane) * 8],
                     &Vs[0][(w * 2 + p) * 512]);
        }
    }

    for (int kt = 0; kt <= qt; ++kt) {
        const int cur = kt & 1;
        __syncthreads();   // drains buf[cur] DMA (vmcnt0 before barrier) + syncs

        if (kt < qt) {     // issue next-tile DMA into the other buffer
            const int nxt = cur ^ 1;
            const size_t kvb = (tok + (kt + 1) * 64) * 3072 + h * 64;
            const u16* vs2 = vsrc + (size_t)(kt + 1) * 4096;
            #pragma unroll
            for (int p = 0; p < 2; ++p) {
                int kk = p * 32 + kkey_l;
                gl_lds16(&qkv[kvb + (size_t)kk * 3072 + 1024 + ((ksch ^ (kk & 7)) << 3)],
                         &Ks[nxt][(p * 32 + w * 8) * 64]);
                gl_lds16(&vs2[(size_t)((w * 2 + p) * 64 + lane) * 8],
                         &Vs[nxt][(w * 2 + p) * 512]);
            }
        }

        // S^T = K . Q^T : 4 key sub-tiles of 16
        f32x4 sacc[4];
        __builtin_amdgcn_s_setprio(1);
        #pragma unroll
        for (int s = 0; s < 4; ++s) {
            int key = s * 16 + ln;
            f32x4 a = fz;
            #pragma unroll
            for (int t2 = 0; t2 < 2; ++t2) {
                bf16x8 kf = *(const bf16x8*)&Ks[cur][key * 64 + (((t2 * 4 + hi) ^ (key & 7)) << 3)];
                a = MFMA16(kf, qb[t2], a);
            }
            sacc[s] = a;
        }
        __builtin_amdgcn_s_setprio(0);

        // online softmax, exp2 domain (lane owns one q-row; reduce over hi)
        float p_[16];
        float mloc = -1e30f;
        if (kt == qt) {
            #pragma unroll
            for (int s = 0; s < 4; ++s)
                #pragma unroll
                for (int r = 0; r < 4; ++r) {
                    int keyg = kt * 64 + s * 16 + hi * 4 + r;
                    float v = (keyg <= qrow) ? sacc[s][r] : -1e30f;
                    p_[s * 4 + r] = v;
                    mloc = fmaxf(mloc, v);
                }
        } else {
            #pragma unroll
            for (int s = 0; s < 4; ++s)
                #pragma unroll
                for (int r = 0; r < 4; ++r) {
                    float v = sacc[s][r];
                    p_[s * 4 + r] = v;
                    mloc = fmaxf(mloc, v);
                }
        }
        mloc = fmaxf(mloc, __shfl_xor(mloc, 16));
        mloc = fmaxf(mloc, __shfl_xor(mloc, 32));
        // defer-max: rescale only if some row's max grew past THR=8 (2^8 headroom)
        if (!__all(mloc - m_run <= 8.f)) {
            float m_new = fmaxf(m_run, mloc);
            float alpha = EXP2F(m_run - m_new);
            l_run *= alpha;
            #pragma unroll
            for (int dt = 0; dt < 4; ++dt) o[dt] *= alpha;
            m_run = m_new;
        }
        float lsum = 0.f;
        #pragma unroll
        for (int i = 0; i < 16; ++i) {
            float e = EXP2F(p_[i] - m_run);
            p_[i] = e;
            lsum += e;
        }
        lsum += __shfl_xor(lsum, 16);
        lsum += __shfl_xor(lsum, 32);
        l_run += lsum;

        // P -> bf16 fragments via packed convert (identity key bijection)
        bf16x8 pa[2];
        #pragma unroll
        for (int k2 = 0; k2 < 2; ++k2) {
            union { unsigned wd[4]; bf16x8 v; } pu;
            #pragma unroll
            for (int qi = 0; qi < 4; ++qi)
                asm("v_cvt_pk_bf16_f32 %0, %1, %2"
                    : "=v"(pu.wd[qi])
                    : "v"(p_[k2 * 8 + 2 * qi]), "v"(p_[k2 * 8 + 2 * qi + 1]));
            pa[k2] = pu.v;
        }

        // O^T += V^T . P^T ; blocked V: one b128 per (dt,k2),
        // slot i = V[key 32k2 + 16(i>>2) + 4hi + (i&3)][d]  (= pa key map)
        __builtin_amdgcn_s_setprio(1);
        #pragma unroll
        for (int dt = 0; dt < 4; ++dt)
            #pragma unroll
            for (int k2 = 0; k2 < 2; ++k2) {
                bf16x8 va = *(const bf16x8*)&Vs[cur][(size_t)((k2 * 4 + hi) * 64 + dt * 16 + ln) * 8];
                o[dt] = MFMA16(va, pa[k2], o[dt]);
            }
        __builtin_amdgcn_s_setprio(0);
    }

    // epilogue: lane owns qrow; d = dt*16 + hi*4 + r
    float inv = 1.f / l_run;
    #pragma unroll
    for (int dt = 0; dt < 4; ++dt) {
        ushort4 ov;
        ov.x = f2bf(o[dt][0] * inv);
        ov.y = f2bf(o[dt][1] * inv);
        ov.z = f2bf(o[dt][2] * inv);
        ov.w = f2bf(o[dt][3] * inv);
        *(ushort4*)&ctx[(tok + qrow) * 1024 + h * 64 + dt * 16 + hi * 4] = ov;
    }
}

extern "C" void kernel_launch(void* const* d_in, const int* in_sizes, int n_in,
                              void* d_out, int out_size, void* d_ws, size_t ws_size,
                              hipStream_t stream) {
    const float* hs     = (const float*)d_in[0];   // [2,2048,1024]
    const float* w_attn = (const float*)d_in[1];   // [1024,3072]
    const float* b_attn = (const float*)d_in[2];   // [3072]
    const float* w_proj = (const float*)d_in[3];   // [1024,1024]
    const float* b_proj = (const float*)d_in[4];   // [1024]
    float* out = (float*)d_out;                    // [2,2048,1024] fp32

    char* ws = (char*)d_ws;
    u16* hsb  = (u16*)ws;                          // 8 MB
    u16* waT  = (u16*)(ws + ((size_t)8  << 20));   // 6 MB  [3072][1024]
    u16* wpT  = (u16*)(ws + ((size_t)14 << 20));   // 2 MB  [1024][1024]
    u16* qkvb = (u16*)(ws + ((size_t)16 << 20));   // 24 MB [4096][3072]
    u16* ctxb = (u16*)(ws + ((size_t)40 << 20));   // 8 MB  [4096][1024]
    u16* vtg  = (u16*)(ws + ((size_t)48 << 20));   // 8 MB  blocked V^T

    cast_bf16<<<4096, 256, 0, stream>>>(hs, hsb, NT * 1024);
    transpose_cast<<<dim3(16, 48), 256, 0, stream>>>(w_attn, waT, 3072);
    transpose_cast<<<dim3(16, 16), 256, 0, stream>>>(w_proj, wpT, 1024);

    gemm_bt<3072, u16><<<dim3(NT / 128, 3072 / 128), 256, 0, stream>>>(hsb, waT, b_attn, qkvb);
    transpose_v<<<dim3(BB * 16, SS / 64), 256, 0, stream>>>(qkvb, vtg);
    attn_mfma<<<dim3(BB * 16, SS / 64), 256, 0, stream>>>(qkvb, vtg, ctxb);
    gemm_bt<1024, float><<<dim3(NT / 128, 1024 / 128), 256, 0, stream>>>(ctxb, wpT, b_proj, out);
}